// Round 1
// baseline (303.969 us; speedup 1.0000x reference)
//
#include <hip/hip_runtime.h>

// Problem constants (fixed by setup_inputs)
static constexpr int   Bn   = 32;
static constexpr int   Hn   = 512;
static constexpr int   Wn   = 512;
static constexpr int   HWn  = Hn * Wn;          // 262144
static constexpr int   CAP  = 2048;             // per-batch coord capacity (expected ~262, 6 sigma ~360)
static constexpr int   RAD  = 7;                // exp(-32) ~ 1.3e-14: below fp32 noise vs threshold
static constexpr int   WIN  = 2 * RAD + 1;      // 15
static constexpr float SIGMA_X = 1.0f;
static constexpr float SIGMA_Y = 1.0f;

// ws layout: [0,32) counts (int), [32,64) per-batch max (uint bits), [64, 64+32*CAP) coords
// total = (64 + 32*2048)*4 = 262,400 bytes

// Kernel 1: copy channels 0,1,3; zero channel 2 in out; detect mask nonzeros.
// One thread per 4 consecutive w. Fully coalesced float4 traffic.
__global__ __launch_bounds__(256) void k_copy_detect(
    const float* __restrict__ x, float* __restrict__ out,
    int* __restrict__ counts, int* __restrict__ coords)
{
    const int plane4 = HWn / 4;                 // 65536 float4 per plane
    int t = blockIdx.x * 256 + threadIdx.x;     // 0 .. Bn*plane4-1
    int b = t / plane4;
    int q = t - b * plane4;
    size_t base = (size_t)b * 4 * HWn;
    const float4* xp = (const float4*)(x + base);
    float4*       op = (float4*)(out + base);

    op[0 * plane4 + q] = xp[0 * plane4 + q];
    op[1 * plane4 + q] = xp[1 * plane4 + q];
    op[3 * plane4 + q] = xp[3 * plane4 + q];
    float4 v = xp[2 * plane4 + q];
    op[2 * plane4 + q] = make_float4(0.f, 0.f, 0.f, 0.f);

    int hw = q * 4;
    if (v.x > 0.f) { int i = atomicAdd(&counts[b], 1); if (i < CAP) coords[b * CAP + i] = hw;     }
    if (v.y > 0.f) { int i = atomicAdd(&counts[b], 1); if (i < CAP) coords[b * CAP + i] = hw + 1; }
    if (v.z > 0.f) { int i = atomicAdd(&counts[b], 1); if (i < CAP) coords[b * CAP + i] = hw + 2; }
    if (v.w > 0.f) { int i = atomicAdd(&counts[b], 1); if (i < CAP) coords[b * CAP + i] = hw + 3; }
}

// Kernel 2: scatter truncated separable Gaussian windows into out channel 2.
// grid = (Bn, SPLIT); each (b, y) slice strides over the n*WIN*WIN work items.
__global__ __launch_bounds__(256) void k_scatter(
    const int* __restrict__ counts, const int* __restrict__ coords,
    float* __restrict__ out)
{
    __shared__ float wx[WIN], wy[WIN];
    if (threadIdx.x < WIN) {
        float d = (float)((int)threadIdx.x - RAD);
        wx[threadIdx.x] = expf(-(d * d) / (2.f * SIGMA_X * SIGMA_X));
        wy[threadIdx.x] = expf(-(d * d) / (2.f * SIGMA_Y * SIGMA_Y));
    }
    __syncthreads();

    int b = blockIdx.x;
    int n = counts[b]; if (n > CAP) n = CAP;
    float* g = out + ((size_t)b * 4 + 2) * HWn;
    int total  = n * (WIN * WIN);
    int stride = gridDim.y * blockDim.x;
    for (int idx = blockIdx.y * blockDim.x + threadIdx.x; idx < total; idx += stride) {
        int p    = idx / (WIN * WIN);
        int cell = idx - p * (WIN * WIN);
        int c  = coords[b * CAP + p];
        int i  = c >> 9;                 // Wn = 512
        int j  = c & (Wn - 1);
        int dh = cell / WIN;
        int dw = cell - dh * WIN;
        int h  = i + dh - RAD;
        int w  = j + dw - RAD;
        if ((unsigned)h < (unsigned)Hn && (unsigned)w < (unsigned)Wn)
            atomicAdd(&g[h * Wn + w], wx[dh] * wy[dw]);
    }
}

// Kernel 3: per-batch max of out channel 2 (values >= 0, so float bits order as uint).
__global__ __launch_bounds__(256) void k_max(
    const float* __restrict__ out, unsigned int* __restrict__ m)
{
    int b = blockIdx.x;
    const float4* g = (const float4*)(out + ((size_t)b * 4 + 2) * HWn);
    const int plane4 = HWn / 4;
    int per   = plane4 / gridDim.y;
    int start = blockIdx.y * per;
    float mx = 0.f;
    for (int idx = start + threadIdx.x; idx < start + per; idx += blockDim.x) {
        float4 v = g[idx];
        mx = fmaxf(mx, fmaxf(fmaxf(v.x, v.y), fmaxf(v.z, v.w)));
    }
    for (int o = 32; o > 0; o >>= 1) mx = fmaxf(mx, __shfl_down(mx, o));
    __shared__ float smx[4];
    if ((threadIdx.x & 63) == 0) smx[threadIdx.x >> 6] = mx;
    __syncthreads();
    if (threadIdx.x == 0) {
        mx = fmaxf(fmaxf(smx[0], smx[1]), fmaxf(smx[2], smx[3]));
        atomicMax(&m[b], __float_as_uint(mx));
    }
}

// Kernel 4: normalize channel 2 in place by per-batch max (0 -> 1).
__global__ __launch_bounds__(256) void k_norm(
    float* __restrict__ out, const unsigned int* __restrict__ m)
{
    const int plane4 = HWn / 4;
    int t = blockIdx.x * 256 + threadIdx.x;
    int b = t / plane4;
    int q = t - b * plane4;
    float mv = __uint_as_float(m[b]);
    float s  = (mv == 0.f) ? 1.f : 1.f / mv;
    float4* g = (float4*)(out + ((size_t)b * 4 + 2) * HWn);
    float4 v = g[q];
    v.x *= s; v.y *= s; v.z *= s; v.w *= s;
    g[q] = v;
}

extern "C" void kernel_launch(void* const* d_in, const int* in_sizes, int n_in,
                              void* d_out, int out_size, void* d_ws, size_t ws_size,
                              hipStream_t stream) {
    const float* x = (const float*)d_in[0];
    float* out = (float*)d_out;

    int*          counts = (int*)d_ws;
    unsigned int* m      = (unsigned int*)d_ws + 32;
    int*          coords = (int*)d_ws + 64;

    // zero counters + maxes (ws is re-poisoned to 0xAA before every launch)
    hipMemsetAsync(d_ws, 0, 64 * sizeof(int), stream);

    const int total4 = Bn * HWn / 4;            // 2,097,152 threads
    k_copy_detect<<<total4 / 256, 256, 0, stream>>>(x, out, counts, coords);
    k_scatter   <<<dim3(Bn, 8),  256, 0, stream>>>(counts, coords, out);
    k_max       <<<dim3(Bn, 8),  256, 0, stream>>>(out, m);
    k_norm      <<<total4 / 256, 256, 0, stream>>>(out, m);
}